// Round 17
// baseline (280.985 us; speedup 1.0000x reference)
//
#include <hip/hip_runtime.h>
#include <math.h>

#define N_NODES 50000
#define N_EDGES 500000
#define D_IN 512
#define D_H  512
#define D_OUT 256
#define NB 196    // ceil(N_NODES/256)
#define NBK 1954  // ceil(N_EDGES/256)

typedef __attribute__((ext_vector_type(8))) short bf16x8;
typedef __attribute__((ext_vector_type(8))) unsigned short ushort8;
typedef __attribute__((ext_vector_type(4))) float f32x4;

__device__ __forceinline__ float b2f(unsigned short u) {
    union { unsigned int i; float f; } v; v.i = ((unsigned int)u) << 16; return v.f;
}
__device__ __forceinline__ unsigned short f2b(float f) {
    unsigned int x = __float_as_uint(f);
    unsigned int r = (x + 0x7fffu + ((x >> 16) & 1u)) >> 16;  // RNE
    return (unsigned short)r;
}

// ---------------- fused prep: indeg-hist + cvt(x->bf16) + wt(W1) + wt(W2) -------

#define CB   12500                      // (N_NODES*D_IN/8)/256: cvt region
#define W1B  256                        // (D_IN/32)*(D_H/32)
#define W2B  128                        // (D_H/32)*(D_OUT/32)

__global__ __launch_bounds__(256) void k_prep(const float* __restrict__ x,
                                              unsigned short* __restrict__ xb,
                                              const float* __restrict__ W1,
                                              unsigned short* __restrict__ W1t,
                                              const float* __restrict__ W2,
                                              unsigned short* __restrict__ W2t,
                                              const int* __restrict__ dst,
                                              int* __restrict__ indeg) {
    __shared__ float t[32][33];
    int b = blockIdx.x;
    const int tid = threadIdx.x;

    if (b < NBK) {  // in-degree histogram
        const int e = b * 256 + tid;
        if (e < N_EDGES) atomicAdd(&indeg[dst[e]], 1);
        return;
    }
    b -= NBK;
    if (b < CB) {   // x fp32 -> bf16 (BW-bound; hist hides under it)
        const long long i = (long long)b * 256 + tid;  // ushort8 units
        float4 v0 = ((const float4*)x)[i * 2];
        float4 v1 = ((const float4*)x)[i * 2 + 1];
        ushort8 o;
        o[0] = f2b(v0.x); o[1] = f2b(v0.y); o[2] = f2b(v0.z); o[3] = f2b(v0.w);
        o[4] = f2b(v1.x); o[5] = f2b(v1.y); o[6] = f2b(v1.z); o[7] = f2b(v1.w);
        ((ushort8*)xb)[i] = o;
        return;
    }
    b -= CB;
    // weight transpose: W [K][N] fp32 -> Wt [N][K] bf16, 32x32 tiles
    const float* W;
    unsigned short* Wt;
    int K, N, idx;
    if (b < W1B) { W = W1; Wt = W1t; K = D_IN; N = D_H; idx = b; }
    else         { W = W2; Wt = W2t; K = D_H; N = D_OUT; idx = b - W1B; }
    const int nkb = K / 32;
    const int bk = (idx % nkb) * 32;
    const int bn = (idx / nkb) * 32;
    const int tx = tid & 31, ty = tid >> 5;  // (32,8)
    for (int i = ty; i < 32; i += 8) t[i][tx] = W[(size_t)(bk + i) * N + bn + tx];
    __syncthreads();
    for (int i = ty; i < 32; i += 8)
        Wt[(size_t)(bn + i) * K + bk + tx] = f2b(t[tx][i]);
}

// ---------------- CSR scan chain ----------------

__global__ __launch_bounds__(256) void k_partials(const int* __restrict__ indeg,
                                                  int* __restrict__ bsum) {
    __shared__ int wsum[4];
    const int tid = threadIdx.x, lane = tid & 63, w = tid >> 6;
    const int i = blockIdx.x * 256 + tid;
    int v = (i < N_NODES) ? indeg[i] : 0;
#pragma unroll
    for (int o = 32; o > 0; o >>= 1) v += __shfl_down(v, o, 64);
    if (lane == 0) wsum[w] = v;
    __syncthreads();
    if (tid == 0) bsum[blockIdx.x] = wsum[0] + wsum[1] + wsum[2] + wsum[3];
}

__global__ __launch_bounds__(256) void k_scanb(const int* __restrict__ bsum,
                                               int* __restrict__ boff) {
    __shared__ int wsum[4];
    const int tid = threadIdx.x, lane = tid & 63, w = tid >> 6;
    const int v = (tid < NB) ? bsum[tid] : 0;
    int s = v;
#pragma unroll
    for (int o = 1; o < 64; o <<= 1) {
        int t = __shfl_up(s, o, 64);
        if (lane >= o) s += t;
    }
    if (lane == 63) wsum[w] = s;
    __syncthreads();
    int add = 0;
    for (int k = 0; k < w; ++k) add += wsum[k];
    if (tid < NB) boff[tid] = add + s - v;
}

__global__ __launch_bounds__(256) void k_finalize(const int* __restrict__ indeg,
                                                  const int* __restrict__ boff,
                                                  int* __restrict__ row_start,
                                                  int* __restrict__ cursor,
                                                  float* __restrict__ dinv) {
    __shared__ int wsum[4];
    const int tid = threadIdx.x, lane = tid & 63, w = tid >> 6;
    const int i = blockIdx.x * 256 + tid;
    const int v = (i < N_NODES) ? indeg[i] : 0;
    int s = v;
#pragma unroll
    for (int o = 1; o < 64; o <<= 1) {
        int t = __shfl_up(s, o, 64);
        if (lane >= o) s += t;
    }
    if (lane == 63) wsum[w] = s;
    __syncthreads();
    int add = boff[blockIdx.x];
    for (int k = 0; k < w; ++k) add += wsum[k];
    if (i < N_NODES) {
        const int excl = add + s - v;
        row_start[i] = excl;
        cursor[i] = excl;
        dinv[i] = rsqrtf((float)(1 + v));
    }
    if (i == N_NODES) row_start[N_NODES] = N_EDGES;
}

// ---------------- 128x128 bf16 GEMM, BK=32, TRIPLE-buffered, counted vmcnt ------
// C'[r,:] = rowscale[r] * (A @ Bt^T)[r,:].  4 waves 2x2; per-wave 64x64.
// T3/T4: 3 LDS buffers (48 KB, 3 blocks/CU); per step issue stage(t+2), compute
// buf(t), then s_waitcnt vmcnt(4) (drains stage(t+1), leaves stage(t+2) flying)
// + raw s_barrier. Per-wave vmcnt-then-barrier => cross-wave stage(t+1) complete.
// Swizzle swz(row)=(row>>1)&3 (R16-verified 0 conflicts). Vec epilogue reuses LDS.

__device__ __forceinline__ void gload16(const void* g, void* l) {
    __builtin_amdgcn_global_load_lds(
        (const __attribute__((address_space(1))) unsigned int*)g,
        (__attribute__((address_space(3))) unsigned int*)l, 16, 0, 0);
}

template <bool FUSE_BUCKET>
__global__ __launch_bounds__(256, 4) void k_gemm(const unsigned short* __restrict__ A,
                                                 const unsigned short* __restrict__ Bt,
                                                 unsigned short* __restrict__ C,
                                                 const float* __restrict__ rowscale,
                                                 int M, int N, int K,
                                                 int ncb, int nrb,
                                                 const int* __restrict__ src,
                                                 const int* __restrict__ dst,
                                                 int* __restrict__ cursor,
                                                 int* __restrict__ csr_src) {
    // A bufs: [0,4096),[4096,8192),[8192,12288); B bufs: 12288 + same (shorts)
    __shared__ __align__(16) short lds[24576];

    if (FUSE_BUCKET && blockIdx.x < NBK) {
        const int e = blockIdx.x * 256 + threadIdx.x;
        if (e < N_EDGES) {
            const int pos = atomicAdd(&cursor[dst[e]], 1);
            csr_src[pos] = src[e];
        }
        return;
    }
    const int bid = blockIdx.x - (FUSE_BUCKET ? NBK : 0);
    const int xcd = bid & 7;
    const int sidx = bid >> 3;
    const int cb = sidx % ncb;
    const int rb = (sidx / ncb) * 8 + xcd;
    if (rb >= nrb) return;
    const int brow = rb * 128;
    const int bcol = cb * 128;

    const int tid = threadIdx.x;
    const int wid = tid >> 6;
    const int lane = tid & 63;
    const int wr = wid >> 1, wc = wid & 1;
    const int lhi = lane >> 4, llo = lane & 15;

    f32x4 acc[4][4];
#pragma unroll
    for (int i = 0; i < 4; ++i)
#pragma unroll
        for (int j = 0; j < 4; ++j) acc[i][j] = (f32x4){0.f, 0.f, 0.f, 0.f};

    // slot: s = g*256+tid (g<2); row = s>>2; src chunk = (s&3) ^ ((s>>3)&3)
#define STAGE(bufidx, kt)                                                       \
    {                                                                           \
        _Pragma("unroll") for (int g = 0; g < 2; ++g) {                         \
            const int s = g * 256 + tid;                                        \
            const int row = s >> 2;                                             \
            const int sc = (s & 3) ^ ((s >> 3) & 3);                            \
            int gr = brow + row; gr = gr < M ? gr : M - 1;                      \
            gload16(A + (size_t)gr * K + (kt) + sc * 8,                         \
                    &lds[(bufidx) * 4096 + (g * 256 + wid * 64) * 8]);          \
            gload16(Bt + (size_t)(bcol + row) * K + (kt) + sc * 8,              \
                    &lds[12288 + (bufidx) * 4096 + (g * 256 + wid * 64) * 8]);  \
        }                                                                       \
    }

    const int nt = K / 32;  // 16 (>= 2)

    // prologue: stage tiles 0,1 into bufs 0,1; drain stage0 only
    STAGE(0, 0);
    STAGE(1, 32);
    asm volatile("s_waitcnt vmcnt(4)" ::: "memory");
    __builtin_amdgcn_s_barrier();
    __builtin_amdgcn_sched_barrier(0);

    int b0 = 0, b1 = 1, b2 = 2;
    for (int t = 0; t < nt; ++t) {
        if (t + 2 < nt) STAGE(b2, (t + 2) * 32);

        bf16x8 af[4], bf[4];
#pragma unroll
        for (int mi = 0; mi < 4; ++mi) {
            const int row = wr * 64 + mi * 16 + llo;
            af[mi] = *(const bf16x8*)&lds[b0 * 4096 + row * 32 + ((lhi ^ ((row >> 1) & 3)) * 8)];
        }
#pragma unroll
        for (int ni = 0; ni < 4; ++ni) {
            const int row = wc * 64 + ni * 16 + llo;
            bf[ni] = *(const bf16x8*)&lds[12288 + b0 * 4096 + row * 32 + ((lhi ^ ((row >> 1) & 3)) * 8)];
        }
#pragma unroll
        for (int mi = 0; mi < 4; ++mi)
#pragma unroll
            for (int ni = 0; ni < 4; ++ni)
                acc[mi][ni] = __builtin_amdgcn_mfma_f32_16x16x32_bf16(
                    af[mi], bf[ni], acc[mi][ni], 0, 0, 0);

        // counted drain: stage(t+1) must be done; stage(t+2) may stay in flight
        if (t + 2 < nt) {
            asm volatile("s_waitcnt vmcnt(4)" ::: "memory");
        } else {
            asm volatile("s_waitcnt vmcnt(0)" ::: "memory");
        }
        __builtin_amdgcn_s_barrier();
        __builtin_amdgcn_sched_barrier(0);

        const int tmp = b0; b0 = b1; b1 = b2; b2 = tmp;
    }
#undef STAGE

    // epilogue: rowscale, per-wave 64x64 swizzled LDS tile, dwordx4 stores
    short* cws = &lds[wid * 4096];  // [64 rows][8 chunks of 8], chunk ^= (row&7)

#pragma unroll
    for (int mi = 0; mi < 4; ++mi) {
#pragma unroll
        for (int r = 0; r < 4; ++r) {
            const int lrow = mi * 16 + lhi * 4 + r;
            int grow = brow + wr * 64 + lrow;
            grow = grow < M ? grow : M - 1;
            const float ds = rowscale[grow];
#pragma unroll
            for (int ni = 0; ni < 4; ++ni) {
                const int col = ni * 16 + llo;
                const int chunk = (col >> 3) ^ (lrow & 7);
                cws[lrow * 64 + chunk * 8 + (col & 7)] = (short)f2b(acc[mi][ni][r] * ds);
            }
        }
    }
    __syncthreads();

    {
        const int rsub = lane >> 3;
        const int c = lane & 7;
#pragma unroll
        for (int i = 0; i < 8; ++i) {
            const int row = i * 8 + rsub;
            const ushort8 o = *(const ushort8*)&cws[row * 64 + ((c ^ (row & 7)) * 8)];
            const int grow = brow + wr * 64 + row;
            if (grow < M)
                *(ushort8*)(C + (size_t)grow * N + bcol + wc * 64 + c * 8) = o;
        }
    }
}

// ---------------- fused aggregate on pre-scaled H': sum + dinv[d] + bias + ELU ---

template <int D, bool BF16_OUT>
__global__ __launch_bounds__(256) void k_aggregate(const unsigned short* __restrict__ H,
                                                   const float* __restrict__ bias,
                                                   void* __restrict__ outv,
                                                   const int* __restrict__ row_start,
                                                   const int* __restrict__ csr_src,
                                                   const float* __restrict__ dinv) {
    const int wid = threadIdx.x >> 6;
    const int lane = threadIdx.x & 63;
    int n, c0;
    if (D == 512) { n = blockIdx.x * 4 + wid; c0 = lane * 8; }
    else          { n = blockIdx.x * 8 + wid * 2 + (lane >> 5); c0 = (lane & 31) * 8; }
    if (n >= N_NODES) return;

    float acc[8];
    {
        ushort8 v = *(const ushort8*)(H + (size_t)n * D + c0);
#pragma unroll
        for (int e = 0; e < 8; ++e) acc[e] = b2f(v[e]);
    }

    const int e0 = row_start[n];
    const int e1 = row_start[n + 1];
    int j = e0;
    for (; j + 8 <= e1; j += 8) {
        int s[8];
#pragma unroll
        for (int q = 0; q < 8; ++q) s[q] = csr_src[j + q];
#pragma unroll
        for (int h = 0; h < 2; ++h) {
            const ushort8 v0 = *(const ushort8*)(H + (size_t)s[h * 4 + 0] * D + c0);
            const ushort8 v1 = *(const ushort8*)(H + (size_t)s[h * 4 + 1] * D + c0);
            const ushort8 v2 = *(const ushort8*)(H + (size_t)s[h * 4 + 2] * D + c0);
            const ushort8 v3 = *(const ushort8*)(H + (size_t)s[h * 4 + 3] * D + c0);
#pragma unroll
            for (int e = 0; e < 8; ++e) {
                acc[e] += b2f(v0[e]);
                acc[e] += b2f(v1[e]);
                acc[e] += b2f(v2[e]);
                acc[e] += b2f(v3[e]);
            }
        }
    }
    for (; j + 4 <= e1; j += 4) {
        const int s0 = csr_src[j + 0];
        const int s1 = csr_src[j + 1];
        const int s2 = csr_src[j + 2];
        const int s3 = csr_src[j + 3];
        const ushort8 v0 = *(const ushort8*)(H + (size_t)s0 * D + c0);
        const ushort8 v1 = *(const ushort8*)(H + (size_t)s1 * D + c0);
        const ushort8 v2 = *(const ushort8*)(H + (size_t)s2 * D + c0);
        const ushort8 v3 = *(const ushort8*)(H + (size_t)s3 * D + c0);
#pragma unroll
        for (int e = 0; e < 8; ++e) {
            acc[e] += b2f(v0[e]);
            acc[e] += b2f(v1[e]);
            acc[e] += b2f(v2[e]);
            acc[e] += b2f(v3[e]);
        }
    }
    for (; j < e1; ++j) {
        const int s = csr_src[j];
        const ushort8 v = *(const ushort8*)(H + (size_t)s * D + c0);
#pragma unroll
        for (int e = 0; e < 8; ++e) acc[e] += b2f(v[e]);
    }

    const float di = dinv[n];
#pragma unroll
    for (int e = 0; e < 8; ++e) {
        float t = fmaf(acc[e], di, bias[c0 + e]);
        acc[e] = t > 0.f ? t : expf(t) - 1.f;
    }

    if (BF16_OUT) {
        ushort8 o;
#pragma unroll
        for (int e = 0; e < 8; ++e) o[e] = f2b(acc[e]);
        *(ushort8*)((unsigned short*)outv + (size_t)n * D + c0) = o;
    } else {
        float* orow = (float*)outv + (size_t)n * D + c0;
        *(float4*)orow = make_float4(acc[0], acc[1], acc[2], acc[3]);
        *(float4*)(orow + 4) = make_float4(acc[4], acc[5], acc[6], acc[7]);
    }
}

// ---------------- launch ----------------

extern "C" void kernel_launch(void* const* d_in, const int* in_sizes, int n_in,
                              void* d_out, int out_size, void* d_ws, size_t ws_size,
                              hipStream_t stream) {
    const float* x  = (const float*)d_in[0];
    const int* ei   = (const int*)d_in[1];
    const int* src  = ei;
    const int* dst  = ei + N_EDGES;
    const float* W1 = (const float*)d_in[2];
    const float* b1 = (const float*)d_in[3];
    const float* W2 = (const float*)d_in[4];
    const float* b2 = (const float*)d_in[5];
    float* out = (float*)d_out;

    char* ws = (char*)d_ws;
    size_t off = 0;
    auto alloc = [&](size_t bytes) -> void* {
        void* p = ws + off;
        off = (off + bytes + 255) & ~(size_t)255;
        return p;
    };
    int*   indeg     = (int*)alloc((size_t)N_NODES * 4);
    int*   bsum      = (int*)alloc((size_t)NB * 4);
    int*   boff      = (int*)alloc((size_t)NB * 4);
    int*   row_start = (int*)alloc((size_t)(N_NODES + 1) * 4);
    int*   cursor    = (int*)alloc((size_t)N_NODES * 4);
    int*   csr_src   = (int*)alloc((size_t)N_EDGES * 4);
    float* dinv      = (float*)alloc((size_t)N_NODES * 4);
    unsigned short* W1t  = (unsigned short*)alloc((size_t)D_H * D_IN * 2);
    unsigned short* W2t  = (unsigned short*)alloc((size_t)D_OUT * D_H * 2);
    unsigned short* xb   = (unsigned short*)alloc((size_t)N_NODES * D_IN * 2);  // 51.2 MB
    unsigned short* H1   = (unsigned short*)alloc((size_t)N_NODES * D_H * 2);   // 51.2 MB
    unsigned short* out1 = (unsigned short*)alloc((size_t)N_NODES * D_H * 2);   // 51.2 MB
    unsigned short* H2   = (unsigned short*)alloc((size_t)N_NODES * D_OUT * 2); // 25.6 MB

    // L0: zero indeg (must precede atomics) — stream-ordered memset
    hipMemsetAsync(indeg, 0, (size_t)N_NODES * 4, stream);
    // L1: fused indeg-hist + cvt + weight transposes
    k_prep<<<NBK + CB + W1B + W2B, 256, 0, stream>>>(x, xb, W1, W1t, W2, W2t, dst, indeg);
    // L2-4: scan chain -> row_start/cursor/dinv
    k_partials<<<NB, 256, 0, stream>>>(indeg, bsum);
    k_scanb<<<1, 256, 0, stream>>>(bsum, boff);
    k_finalize<<<NB, 256, 0, stream>>>(indeg, boff, row_start, cursor, dinv);

    const int nrb = (N_NODES + 127) / 128;  // 391
    const int rgrp = (nrb + 7) / 8;         // 49

    // ----- layer 1 (bucket fused into GEMM1 launch) -----
    {
        const int ncb = D_H / 128;          // 4
        k_gemm<true><<<NBK + 8 * ncb * rgrp, 256, 0, stream>>>(
            xb, W1t, H1, dinv, N_NODES, D_H, D_IN, ncb, nrb, src, dst, cursor, csr_src);
    }
    k_aggregate<512, true><<<(N_NODES + 3) / 4, 256, 0, stream>>>(H1, b1, out1, row_start, csr_src, dinv);

    // ----- layer 2 -----
    {
        const int ncb = D_OUT / 128;        // 2
        k_gemm<false><<<8 * ncb * rgrp, 256, 0, stream>>>(
            out1, W2t, H2, dinv, N_NODES, D_OUT, D_H, ncb, nrb, nullptr, nullptr, nullptr, nullptr);
    }
    k_aggregate<256, false><<<(N_NODES + 7) / 8, 256, 0, stream>>>(H2, b2, out, row_start, csr_src, dinv);
}

// Round 18
// 273.913 us; speedup vs baseline: 1.0258x; 1.0258x over previous
//
#include <hip/hip_runtime.h>
#include <math.h>

#define N_NODES 50000
#define N_EDGES 500000
#define D_IN 512
#define D_H  512
#define D_OUT 256
#define NB 196    // ceil(N_NODES/256)
#define NBK 1954  // ceil(N_EDGES/256)

typedef __attribute__((ext_vector_type(8))) short bf16x8;
typedef __attribute__((ext_vector_type(8))) unsigned short ushort8;
typedef __attribute__((ext_vector_type(4))) float f32x4;

__device__ __forceinline__ float b2f(unsigned short u) {
    union { unsigned int i; float f; } v; v.i = ((unsigned int)u) << 16; return v.f;
}
__device__ __forceinline__ unsigned short f2b(float f) {
    unsigned int x = __float_as_uint(f);
    unsigned int r = (x + 0x7fffu + ((x >> 16) & 1u)) >> 16;  // RNE
    return (unsigned short)r;
}

// ---------------- fused prep: indeg-hist + wt(W1) + wt(W2) ----------------

#define W1B  256                        // (D_IN/32)*(D_H/32)
#define W2B  128                        // (D_H/32)*(D_OUT/32)

__global__ __launch_bounds__(256) void k_prep(const float* __restrict__ W1,
                                              unsigned short* __restrict__ W1t,
                                              const float* __restrict__ W2,
                                              unsigned short* __restrict__ W2t,
                                              const int* __restrict__ dst,
                                              int* __restrict__ indeg) {
    __shared__ float t[32][33];
    int b = blockIdx.x;
    const int tid = threadIdx.x;

    if (b < NBK) {  // in-degree histogram
        const int e = b * 256 + tid;
        if (e < N_EDGES) atomicAdd(&indeg[dst[e]], 1);
        return;
    }
    b -= NBK;
    // weight transpose: W [K][N] fp32 -> Wt [N][K] bf16, 32x32 tiles
    const float* W;
    unsigned short* Wt;
    int K, N, idx;
    if (b < W1B) { W = W1; Wt = W1t; K = D_IN; N = D_H; idx = b; }
    else         { W = W2; Wt = W2t; K = D_H; N = D_OUT; idx = b - W1B; }
    const int nkb = K / 32;
    const int bk = (idx % nkb) * 32;
    const int bn = (idx / nkb) * 32;
    const int tx = tid & 31, ty = tid >> 5;  // (32,8)
    for (int i = ty; i < 32; i += 8) t[i][tx] = W[(size_t)(bk + i) * N + bn + tx];
    __syncthreads();
    for (int i = ty; i < 32; i += 8)
        Wt[(size_t)(bn + i) * K + bk + tx] = f2b(t[tx][i]);
}

// ---------------- CSR scan chain ----------------

__global__ __launch_bounds__(256) void k_partials(const int* __restrict__ indeg,
                                                  int* __restrict__ bsum) {
    __shared__ int wsum[4];
    const int tid = threadIdx.x, lane = tid & 63, w = tid >> 6;
    const int i = blockIdx.x * 256 + tid;
    int v = (i < N_NODES) ? indeg[i] : 0;
#pragma unroll
    for (int o = 32; o > 0; o >>= 1) v += __shfl_down(v, o, 64);
    if (lane == 0) wsum[w] = v;
    __syncthreads();
    if (tid == 0) bsum[blockIdx.x] = wsum[0] + wsum[1] + wsum[2] + wsum[3];
}

__global__ __launch_bounds__(256) void k_scanb(const int* __restrict__ bsum,
                                               int* __restrict__ boff) {
    __shared__ int wsum[4];
    const int tid = threadIdx.x, lane = tid & 63, w = tid >> 6;
    const int v = (tid < NB) ? bsum[tid] : 0;
    int s = v;
#pragma unroll
    for (int o = 1; o < 64; o <<= 1) {
        int t = __shfl_up(s, o, 64);
        if (lane >= o) s += t;
    }
    if (lane == 63) wsum[w] = s;
    __syncthreads();
    int add = 0;
    for (int k = 0; k < w; ++k) add += wsum[k];
    if (tid < NB) boff[tid] = add + s - v;
}

__global__ __launch_bounds__(256) void k_finalize(const int* __restrict__ indeg,
                                                  const int* __restrict__ boff,
                                                  int* __restrict__ row_start,
                                                  int* __restrict__ cursor,
                                                  float* __restrict__ dinv) {
    __shared__ int wsum[4];
    const int tid = threadIdx.x, lane = tid & 63, w = tid >> 6;
    const int i = blockIdx.x * 256 + tid;
    const int v = (i < N_NODES) ? indeg[i] : 0;
    int s = v;
#pragma unroll
    for (int o = 1; o < 64; o <<= 1) {
        int t = __shfl_up(s, o, 64);
        if (lane >= o) s += t;
    }
    if (lane == 63) wsum[w] = s;
    __syncthreads();
    int add = boff[blockIdx.x];
    for (int k = 0; k < w; ++k) add += wsum[k];
    if (i < N_NODES) {
        const int excl = add + s - v;
        row_start[i] = excl;
        cursor[i] = excl;
        dinv[i] = rsqrtf((float)(1 + v));
    }
    if (i == N_NODES) row_start[N_NODES] = N_EDGES;
}

// ---------------- 128x128 bf16 GEMM, BK=32, counted vmcnt pipeline --------------
// C'[r,:] = rowscale[r] * (A @ Bt^T)[r,:].  4 waves 2x2; per-wave 64x64.
// A32 (GEMM1): A fp32 via carry-one-step reg pipeline — LOAD_A32(t+2) issued at
//   step t, cvt+ds_write committed at step t+1 (full step of latency hiding);
//   A = 2 LDS bufs, B = 3 bufs (gload_lds, counted vmcnt(6)) -> 40 KB, 4 blk/CU.
// A16 (GEMM2): R17 structure — both operands gload_lds, 3+3 bufs, vmcnt(4),
//   48 KB, 3 blk/CU.
// Swizzle swz(row)=(row>>1)&3 (R16-verified 0 conflicts). Vec epilogue reuses LDS.

__device__ __forceinline__ void gload16(const void* g, void* l) {
    __builtin_amdgcn_global_load_lds(
        (const __attribute__((address_space(1))) unsigned int*)g,
        (__attribute__((address_space(3))) unsigned int*)l, 16, 0, 0);
}

template <bool A32, bool FUSE_BUCKET>
__global__ __launch_bounds__(256, A32 ? 4 : 3)
void k_gemm(const void* __restrict__ Av,
            const unsigned short* __restrict__ Bt,
            unsigned short* __restrict__ C,
            const float* __restrict__ rowscale,
            int M, int N, int K,
            int ncb, int nrb,
            const int* __restrict__ src,
            const int* __restrict__ dst,
            int* __restrict__ cursor,
            int* __restrict__ csr_src) {
    constexpr int ABUFS = A32 ? 2 : 3;
    constexpr int BBASE = ABUFS * 4096;
    __shared__ __align__(16) short lds[(ABUFS + 3) * 4096];

    if (FUSE_BUCKET && blockIdx.x < NBK) {
        const int e = blockIdx.x * 256 + threadIdx.x;
        if (e < N_EDGES) {
            const int pos = atomicAdd(&cursor[dst[e]], 1);
            csr_src[pos] = src[e];
        }
        return;
    }
    const int bid = blockIdx.x - (FUSE_BUCKET ? NBK : 0);
    const int xcd = bid & 7;
    const int sidx = bid >> 3;
    const int cb = sidx % ncb;
    const int rb = (sidx / ncb) * 8 + xcd;
    if (rb >= nrb) return;
    const int brow = rb * 128;
    const int bcol = cb * 128;

    const int tid = threadIdx.x;
    const int wid = tid >> 6;
    const int lane = tid & 63;
    const int wr = wid >> 1, wc = wid & 1;
    const int lhi = lane >> 4, llo = lane & 15;

    const float* Af = (const float*)Av;
    const unsigned short* Ab = (const unsigned short*)Av;

    f32x4 acc[4][4];
#pragma unroll
    for (int i = 0; i < 4; ++i)
#pragma unroll
        for (int j = 0; j < 4; ++j) acc[i][j] = (f32x4){0.f, 0.f, 0.f, 0.f};

    // slot: s = g*256+tid (g<2); row = s>>2; src chunk = (s&3) ^ ((s>>3)&3)
    float4 ar[2][2];  // A32 carry regs (live across one step)

#define STAGE_A16(bufidx, kt)                                                   \
    {                                                                           \
        _Pragma("unroll") for (int g = 0; g < 2; ++g) {                         \
            const int s = g * 256 + tid;                                        \
            const int row = s >> 2;                                             \
            const int sc = (s & 3) ^ ((s >> 3) & 3);                            \
            int gr = brow + row; gr = gr < M ? gr : M - 1;                      \
            gload16(Ab + (size_t)gr * K + (kt) + sc * 8,                        \
                    &lds[(bufidx) * 4096 + (g * 256 + wid * 64) * 8]);          \
        }                                                                       \
    }
#define STAGE_B(bufidx, kt)                                                     \
    {                                                                           \
        _Pragma("unroll") for (int g = 0; g < 2; ++g) {                         \
            const int s = g * 256 + tid;                                        \
            const int row = s >> 2;                                             \
            const int sc = (s & 3) ^ ((s >> 3) & 3);                            \
            gload16(Bt + (size_t)(bcol + row) * K + (kt) + sc * 8,              \
                    &lds[BBASE + (bufidx) * 4096 + (g * 256 + wid * 64) * 8]);  \
        }                                                                       \
    }
#define LOAD_A32(kt)                                                            \
    {                                                                           \
        _Pragma("unroll") for (int g = 0; g < 2; ++g) {                         \
            const int s = g * 256 + tid;                                        \
            const int row = s >> 2;                                             \
            const int sc = (s & 3) ^ ((s >> 3) & 3);                            \
            int gr = brow + row; gr = gr < M ? gr : M - 1;                      \
            const float* p = Af + (size_t)gr * K + (kt) + sc * 8;               \
            ar[g][0] = *(const float4*)p;                                       \
            ar[g][1] = *(const float4*)(p + 4);                                 \
        }                                                                       \
    }
#define WRITE_A32(bufidx)                                                       \
    {                                                                           \
        _Pragma("unroll") for (int g = 0; g < 2; ++g) {                         \
            ushort8 u;                                                          \
            u[0] = f2b(ar[g][0].x); u[1] = f2b(ar[g][0].y);                     \
            u[2] = f2b(ar[g][0].z); u[3] = f2b(ar[g][0].w);                     \
            u[4] = f2b(ar[g][1].x); u[5] = f2b(ar[g][1].y);                     \
            u[6] = f2b(ar[g][1].z); u[7] = f2b(ar[g][1].w);                     \
            *(ushort8*)&lds[(bufidx) * 4096 + (g * 256 + tid) * 8] = u;         \
        }                                                                       \
    }

    const int nt = K / 32;  // 16

    // ---- prologue ----
    if (A32) {
        LOAD_A32(0);              // A0 -> regs (4 loads)
        STAGE_B(0, 0);            // B0 (2 gloads)
        WRITE_A32(0);             // waits A0 (vmcnt<=2), commits tile 0
        LOAD_A32(32);             // A1 -> regs
        STAGE_B(1, 32);           // B1
        // outstanding: B0(2)+A1(4)+B1(2)=8 -> drain B0
        asm volatile("s_waitcnt vmcnt(6) lgkmcnt(0)" ::: "memory");
    } else {
        STAGE_A16(0, 0);
        STAGE_B(0, 0);
        STAGE_A16(1, 32);
        STAGE_B(1, 32);
        // outstanding: stage0(4)+stage1(4)=8 -> drain stage0
        asm volatile("s_waitcnt vmcnt(4) lgkmcnt(0)" ::: "memory");
    }
    __builtin_amdgcn_s_barrier();
    __builtin_amdgcn_sched_barrier(0);

    int b0 = 0, b1 = 1, b2 = 2;
    for (int t = 0; t < nt; ++t) {
        if (A32) {
            if (t + 1 < nt) WRITE_A32((t + 1) & 1);  // commit tile t+1 (loaded at t-1)
            if (t + 2 < nt) {
                LOAD_A32((t + 2) * 32);
                STAGE_B(b2, (t + 2) * 32);
            }
        } else {
            if (t + 2 < nt) {
                STAGE_A16(b2, (t + 2) * 32);
                STAGE_B(b2, (t + 2) * 32);
            }
        }

        bf16x8 af[4], bf[4];
        const int abase = A32 ? ((t & 1) * 4096) : (b0 * 4096);
#pragma unroll
        for (int mi = 0; mi < 4; ++mi) {
            const int row = wr * 64 + mi * 16 + llo;
            af[mi] = *(const bf16x8*)&lds[abase + row * 32 + ((lhi ^ ((row >> 1) & 3)) * 8)];
        }
#pragma unroll
        for (int ni = 0; ni < 4; ++ni) {
            const int row = wc * 64 + ni * 16 + llo;
            bf[ni] = *(const bf16x8*)&lds[BBASE + b0 * 4096 + row * 32 + ((lhi ^ ((row >> 1) & 3)) * 8)];
        }
#pragma unroll
        for (int mi = 0; mi < 4; ++mi)
#pragma unroll
            for (int ni = 0; ni < 4; ++ni)
                acc[mi][ni] = __builtin_amdgcn_mfma_f32_16x16x32_bf16(
                    af[mi], bf[ni], acc[mi][ni], 0, 0, 0);

        // counted drain: stage(t+1) complete; stage(t+2) stays in flight
        if (t + 2 < nt) {
            if (A32) asm volatile("s_waitcnt vmcnt(6) lgkmcnt(0)" ::: "memory");
            else     asm volatile("s_waitcnt vmcnt(4) lgkmcnt(0)" ::: "memory");
        } else {
            asm volatile("s_waitcnt vmcnt(0) lgkmcnt(0)" ::: "memory");
        }
        __builtin_amdgcn_s_barrier();
        __builtin_amdgcn_sched_barrier(0);

        const int tmp = b0; b0 = b1; b1 = b2; b2 = tmp;
    }
#undef STAGE_A16
#undef STAGE_B
#undef LOAD_A32
#undef WRITE_A32

    // epilogue: rowscale, per-wave 64x64 swizzled LDS tile, dwordx4 stores
    short* cws = &lds[wid * 4096];  // [64 rows][8 chunks of 8], chunk ^= (row&7)

#pragma unroll
    for (int mi = 0; mi < 4; ++mi) {
#pragma unroll
        for (int r = 0; r < 4; ++r) {
            const int lrow = mi * 16 + lhi * 4 + r;
            int grow = brow + wr * 64 + lrow;
            grow = grow < M ? grow : M - 1;
            const float ds = rowscale[grow];
#pragma unroll
            for (int ni = 0; ni < 4; ++ni) {
                const int col = ni * 16 + llo;
                const int chunk = (col >> 3) ^ (lrow & 7);
                cws[lrow * 64 + chunk * 8 + (col & 7)] = (short)f2b(acc[mi][ni][r] * ds);
            }
        }
    }
    __syncthreads();

    {
        const int rsub = lane >> 3;
        const int c = lane & 7;
#pragma unroll
        for (int i = 0; i < 8; ++i) {
            const int row = i * 8 + rsub;
            const ushort8 o = *(const ushort8*)&cws[row * 64 + ((c ^ (row & 7)) * 8)];
            const int grow = brow + wr * 64 + row;
            if (grow < M)
                *(ushort8*)(C + (size_t)grow * N + bcol + wc * 64 + c * 8) = o;
        }
    }
}

// ---------------- fused aggregate on pre-scaled H': sum + dinv[d] + bias + ELU ---

template <int D, bool BF16_OUT>
__global__ __launch_bounds__(256) void k_aggregate(const unsigned short* __restrict__ H,
                                                   const float* __restrict__ bias,
                                                   void* __restrict__ outv,
                                                   const int* __restrict__ row_start,
                                                   const int* __restrict__ csr_src,
                                                   const float* __restrict__ dinv) {
    const int wid = threadIdx.x >> 6;
    const int lane = threadIdx.x & 63;
    int n, c0;
    if (D == 512) { n = blockIdx.x * 4 + wid; c0 = lane * 8; }
    else          { n = blockIdx.x * 8 + wid * 2 + (lane >> 5); c0 = (lane & 31) * 8; }
    if (n >= N_NODES) return;

    float acc[8];
    {
        ushort8 v = *(const ushort8*)(H + (size_t)n * D + c0);
#pragma unroll
        for (int e = 0; e < 8; ++e) acc[e] = b2f(v[e]);
    }

    const int e0 = row_start[n];
    const int e1 = row_start[n + 1];
    int j = e0;
    for (; j + 8 <= e1; j += 8) {
        int s[8];
#pragma unroll
        for (int q = 0; q < 8; ++q) s[q] = csr_src[j + q];
#pragma unroll
        for (int h = 0; h < 2; ++h) {
            const ushort8 v0 = *(const ushort8*)(H + (size_t)s[h * 4 + 0] * D + c0);
            const ushort8 v1 = *(const ushort8*)(H + (size_t)s[h * 4 + 1] * D + c0);
            const ushort8 v2 = *(const ushort8*)(H + (size_t)s[h * 4 + 2] * D + c0);
            const ushort8 v3 = *(const ushort8*)(H + (size_t)s[h * 4 + 3] * D + c0);
#pragma unroll
            for (int e = 0; e < 8; ++e) {
                acc[e] += b2f(v0[e]);
                acc[e] += b2f(v1[e]);
                acc[e] += b2f(v2[e]);
                acc[e] += b2f(v3[e]);
            }
        }
    }
    for (; j + 4 <= e1; j += 4) {
        const int s0 = csr_src[j + 0];
        const int s1 = csr_src[j + 1];
        const int s2 = csr_src[j + 2];
        const int s3 = csr_src[j + 3];
        const ushort8 v0 = *(const ushort8*)(H + (size_t)s0 * D + c0);
        const ushort8 v1 = *(const ushort8*)(H + (size_t)s1 * D + c0);
        const ushort8 v2 = *(const ushort8*)(H + (size_t)s2 * D + c0);
        const ushort8 v3 = *(const ushort8*)(H + (size_t)s3 * D + c0);
#pragma unroll
        for (int e = 0; e < 8; ++e) {
            acc[e] += b2f(v0[e]);
            acc[e] += b2f(v1[e]);
            acc[e] += b2f(v2[e]);
            acc[e] += b2f(v3[e]);
        }
    }
    for (; j < e1; ++j) {
        const int s = csr_src[j];
        const ushort8 v = *(const ushort8*)(H + (size_t)s * D + c0);
#pragma unroll
        for (int e = 0; e < 8; ++e) acc[e] += b2f(v[e]);
    }

    const float di = dinv[n];
#pragma unroll
    for (int e = 0; e < 8; ++e) {
        float t = fmaf(acc[e], di, bias[c0 + e]);
        acc[e] = t > 0.f ? t : expf(t) - 1.f;
    }

    if (BF16_OUT) {
        ushort8 o;
#pragma unroll
        for (int e = 0; e < 8; ++e) o[e] = f2b(acc[e]);
        *(ushort8*)((unsigned short*)outv + (size_t)n * D + c0) = o;
    } else {
        float* orow = (float*)outv + (size_t)n * D + c0;
        *(float4*)orow = make_float4(acc[0], acc[1], acc[2], acc[3]);
        *(float4*)(orow + 4) = make_float4(acc[4], acc[5], acc[6], acc[7]);
    }
}

// ---------------- launch ----------------

extern "C" void kernel_launch(void* const* d_in, const int* in_sizes, int n_in,
                              void* d_out, int out_size, void* d_ws, size_t ws_size,
                              hipStream_t stream) {
    const float* x  = (const float*)d_in[0];
    const int* ei   = (const int*)d_in[1];
    const int* src  = ei;
    const int* dst  = ei + N_EDGES;
    const float* W1 = (const float*)d_in[2];
    const float* b1 = (const float*)d_in[3];
    const float* W2 = (const float*)d_in[4];
    const float* b2 = (const float*)d_in[5];
    float* out = (float*)d_out;

    char* ws = (char*)d_ws;
    size_t off = 0;
    auto alloc = [&](size_t bytes) -> void* {
        void* p = ws + off;
        off = (off + bytes + 255) & ~(size_t)255;
        return p;
    };
    int*   indeg     = (int*)alloc((size_t)N_NODES * 4);
    int*   bsum      = (int*)alloc((size_t)NB * 4);
    int*   boff      = (int*)alloc((size_t)NB * 4);
    int*   row_start = (int*)alloc((size_t)(N_NODES + 1) * 4);
    int*   cursor    = (int*)alloc((size_t)N_NODES * 4);
    int*   csr_src   = (int*)alloc((size_t)N_EDGES * 4);
    float* dinv      = (float*)alloc((size_t)N_NODES * 4);
    unsigned short* W1t  = (unsigned short*)alloc((size_t)D_H * D_IN * 2);
    unsigned short* W2t  = (unsigned short*)alloc((size_t)D_OUT * D_H * 2);
    unsigned short* H1   = (unsigned short*)alloc((size_t)N_NODES * D_H * 2);   // 51.2 MB
    unsigned short* out1 = (unsigned short*)alloc((size_t)N_NODES * D_H * 2);   // 51.2 MB
    unsigned short* H2   = (unsigned short*)alloc((size_t)N_NODES * D_OUT * 2); // 25.6 MB

    // L0: zero indeg (must precede atomics) — stream-ordered memset
    hipMemsetAsync(indeg, 0, (size_t)N_NODES * 4, stream);
    // L1: fused indeg-hist + weight transposes
    k_prep<<<NBK + W1B + W2B, 256, 0, stream>>>(W1, W1t, W2, W2t, dst, indeg);
    // L2-4: scan chain -> row_start/cursor/dinv
    k_partials<<<NB, 256, 0, stream>>>(indeg, bsum);
    k_scanb<<<1, 256, 0, stream>>>(bsum, boff);
    k_finalize<<<NB, 256, 0, stream>>>(indeg, boff, row_start, cursor, dinv);

    const int nrb = (N_NODES + 127) / 128;  // 391
    const int rgrp = (nrb + 7) / 8;         // 49

    // ----- layer 1 (A = x fp32 direct; bucket fused into GEMM1 launch) -----
    {
        const int ncb = D_H / 128;          // 4
        k_gemm<true, true><<<NBK + 8 * ncb * rgrp, 256, 0, stream>>>(
            x, W1t, H1, dinv, N_NODES, D_H, D_IN, ncb, nrb, src, dst, cursor, csr_src);
    }
    k_aggregate<512, true><<<(N_NODES + 3) / 4, 256, 0, stream>>>(H1, b1, out1, row_start, csr_src, dinv);

    // ----- layer 2 -----
    {
        const int ncb = D_OUT / 128;        // 2
        k_gemm<false, false><<<8 * ncb * rgrp, 256, 0, stream>>>(
            out1, W2t, H2, dinv, N_NODES, D_OUT, D_H, ncb, nrb, nullptr, nullptr, nullptr, nullptr);
    }
    k_aggregate<256, false><<<(N_NODES + 7) / 8, 256, 0, stream>>>(H2, b2, out, row_start, csr_src, dinv);
}

// Round 19
// 267.078 us; speedup vs baseline: 1.0521x; 1.0256x over previous
//
#include <hip/hip_runtime.h>
#include <math.h>

#define N_NODES 50000
#define N_EDGES 500000
#define D_IN 512
#define D_H  512
#define D_OUT 256
#define NB 196    // ceil(N_NODES/256)
#define NBK 1954  // ceil(N_EDGES/256)

typedef __attribute__((ext_vector_type(8))) short bf16x8;
typedef __attribute__((ext_vector_type(8))) unsigned short ushort8;
typedef __attribute__((ext_vector_type(4))) float f32x4;

__device__ __forceinline__ float b2f(unsigned short u) {
    union { unsigned int i; float f; } v; v.i = ((unsigned int)u) << 16; return v.f;
}
__device__ __forceinline__ unsigned short f2b(float f) {
    unsigned int x = __float_as_uint(f);
    unsigned int r = (x + 0x7fffu + ((x >> 16) & 1u)) >> 16;  // RNE
    return (unsigned short)r;
}

// ---------------- fused prep: indeg-hist + wt(W1) + wt(W2) ----------------

#define W1B  256                        // (D_IN/32)*(D_H/32)
#define W2B  128                        // (D_H/32)*(D_OUT/32)

__global__ __launch_bounds__(256) void k_prep(const float* __restrict__ W1,
                                              unsigned short* __restrict__ W1t,
                                              const float* __restrict__ W2,
                                              unsigned short* __restrict__ W2t,
                                              const int* __restrict__ dst,
                                              int* __restrict__ indeg) {
    __shared__ float t[32][33];
    int b = blockIdx.x;
    const int tid = threadIdx.x;

    if (b < NBK) {  // in-degree histogram
        const int e = b * 256 + tid;
        if (e < N_EDGES) atomicAdd(&indeg[dst[e]], 1);
        return;
    }
    b -= NBK;
    // weight transpose: W [K][N] fp32 -> Wt [N][K] bf16, 32x32 tiles
    const float* W;
    unsigned short* Wt;
    int K, N, idx;
    if (b < W1B) { W = W1; Wt = W1t; K = D_IN; N = D_H; idx = b; }
    else         { W = W2; Wt = W2t; K = D_H; N = D_OUT; idx = b - W1B; }
    const int nkb = K / 32;
    const int bk = (idx % nkb) * 32;
    const int bn = (idx / nkb) * 32;
    const int tx = tid & 31, ty = tid >> 5;  // (32,8)
    for (int i = ty; i < 32; i += 8) t[i][tx] = W[(size_t)(bk + i) * N + bn + tx];
    __syncthreads();
    for (int i = ty; i < 32; i += 8)
        Wt[(size_t)(bn + i) * K + bk + tx] = f2b(t[tx][i]);
}

// ---------------- CSR scan chain ----------------

__global__ __launch_bounds__(256) void k_partials(const int* __restrict__ indeg,
                                                  int* __restrict__ bsum) {
    __shared__ int wsum[4];
    const int tid = threadIdx.x, lane = tid & 63, w = tid >> 6;
    const int i = blockIdx.x * 256 + tid;
    int v = (i < N_NODES) ? indeg[i] : 0;
#pragma unroll
    for (int o = 32; o > 0; o >>= 1) v += __shfl_down(v, o, 64);
    if (lane == 0) wsum[w] = v;
    __syncthreads();
    if (tid == 0) bsum[blockIdx.x] = wsum[0] + wsum[1] + wsum[2] + wsum[3];
}

__global__ __launch_bounds__(256) void k_scanb(const int* __restrict__ bsum,
                                               int* __restrict__ boff) {
    __shared__ int wsum[4];
    const int tid = threadIdx.x, lane = tid & 63, w = tid >> 6;
    const int v = (tid < NB) ? bsum[tid] : 0;
    int s = v;
#pragma unroll
    for (int o = 1; o < 64; o <<= 1) {
        int t = __shfl_up(s, o, 64);
        if (lane >= o) s += t;
    }
    if (lane == 63) wsum[w] = s;
    __syncthreads();
    int add = 0;
    for (int k = 0; k < w; ++k) add += wsum[k];
    if (tid < NB) boff[tid] = add + s - v;
}

__global__ __launch_bounds__(256) void k_finalize(const int* __restrict__ indeg,
                                                  const int* __restrict__ boff,
                                                  int* __restrict__ row_start,
                                                  int* __restrict__ cursor,
                                                  float* __restrict__ dinv) {
    __shared__ int wsum[4];
    const int tid = threadIdx.x, lane = tid & 63, w = tid >> 6;
    const int i = blockIdx.x * 256 + tid;
    const int v = (i < N_NODES) ? indeg[i] : 0;
    int s = v;
#pragma unroll
    for (int o = 1; o < 64; o <<= 1) {
        int t = __shfl_up(s, o, 64);
        if (lane >= o) s += t;
    }
    if (lane == 63) wsum[w] = s;
    __syncthreads();
    int add = boff[blockIdx.x];
    for (int k = 0; k < w; ++k) add += wsum[k];
    if (i < N_NODES) {
        const int excl = add + s - v;
        row_start[i] = excl;
        cursor[i] = excl;
        dinv[i] = rsqrtf((float)(1 + v));
    }
    if (i == N_NODES) row_start[N_NODES] = N_EDGES;
}

// ---------------- 128x128 bf16 GEMM, BK=32, dbuf, 32 KB LDS, 4 blocks/CU -------
// C'[r,:] = rowscale[r] * (A @ Bt^T)[r,:].  4 waves 2x2; per-wave 64x64.
// Best-measured configuration (R16, 268.9 us total). Swizzle swz(row)=(row>>1)&3
// (verified 0 bank conflicts); launch_bounds (256,4) (VGPR 64, no spill —
// (256,5) spilled catastrophically in R15); A32: A read fp32 directly,
// reg-staged issue-early / cvt+ds_write late; vec epilogue (dwordx4 C stores);
// bijective XCD map for A-panel L2 reuse; bucket fused as launch prefix.

__device__ __forceinline__ void gload16(const void* g, void* l) {
    __builtin_amdgcn_global_load_lds(
        (const __attribute__((address_space(1))) unsigned int*)g,
        (__attribute__((address_space(3))) unsigned int*)l, 16, 0, 0);
}

template <bool A32, bool FUSE_BUCKET>
__global__ __launch_bounds__(256, 4) void k_gemm(const void* __restrict__ Av,
                                                 const unsigned short* __restrict__ Bt,
                                                 unsigned short* __restrict__ C,
                                                 const float* __restrict__ rowscale,
                                                 int M, int N, int K,
                                                 int ncb, int nrb,
                                                 const int* __restrict__ src,
                                                 const int* __restrict__ dst,
                                                 int* __restrict__ cursor,
                                                 int* __restrict__ csr_src) {
    // carve: A bufs [0,4096),[4096,8192); B bufs [8192,12288),[12288,16384) shorts
    __shared__ __align__(16) short lds[16384];

    if (FUSE_BUCKET && blockIdx.x < NBK) {
        const int e = blockIdx.x * 256 + threadIdx.x;
        if (e < N_EDGES) {
            const int pos = atomicAdd(&cursor[dst[e]], 1);
            csr_src[pos] = src[e];
        }
        return;
    }
    const int bid = blockIdx.x - (FUSE_BUCKET ? NBK : 0);
    const int xcd = bid & 7;
    const int sidx = bid >> 3;
    const int cb = sidx % ncb;
    const int rb = (sidx / ncb) * 8 + xcd;
    if (rb >= nrb) return;
    const int brow = rb * 128;
    const int bcol = cb * 128;

    const int tid = threadIdx.x;
    const int wid = tid >> 6;
    const int lane = tid & 63;
    const int wr = wid >> 1, wc = wid & 1;
    const int lhi = lane >> 4, llo = lane & 15;

    const float* Af = (const float*)Av;
    const unsigned short* Ab = (const unsigned short*)Av;

    f32x4 acc[4][4];
#pragma unroll
    for (int i = 0; i < 4; ++i)
#pragma unroll
        for (int j = 0; j < 4; ++j) acc[i][j] = (f32x4){0.f, 0.f, 0.f, 0.f};

    // slot geometry (BK=32): s = g*256+tid (g<2); row = s>>2; pos = s&3;
    // swz(row) = (row>>1)&3 = (s>>3)&3; source chunk sc = pos ^ swz(row).
    float4 ar[2][2];  // A32 reg staging, static-indexed

#define STAGE_A16(buf, kt)                                                      \
    {                                                                           \
        _Pragma("unroll") for (int g = 0; g < 2; ++g) {                         \
            const int s = g * 256 + tid;                                        \
            const int row = s >> 2;                                             \
            const int sc = (s & 3) ^ ((s >> 3) & 3);                            \
            int gr = brow + row; gr = gr < M ? gr : M - 1;                      \
            gload16(Ab + (size_t)gr * K + (kt) + sc * 8,                        \
                    &lds[(buf) * 4096 + (g * 256 + wid * 64) * 8]);             \
        }                                                                       \
    }
#define STAGE_B(buf, kt)                                                        \
    {                                                                           \
        _Pragma("unroll") for (int g = 0; g < 2; ++g) {                         \
            const int s = g * 256 + tid;                                        \
            const int row = s >> 2;                                             \
            const int sc = (s & 3) ^ ((s >> 3) & 3);                            \
            gload16(Bt + (size_t)(bcol + row) * K + (kt) + sc * 8,              \
                    &lds[8192 + (buf) * 4096 + (g * 256 + wid * 64) * 8]);      \
        }                                                                       \
    }
#define LOAD_A32(kt)                                                            \
    {                                                                           \
        _Pragma("unroll") for (int g = 0; g < 2; ++g) {                         \
            const int s = g * 256 + tid;                                        \
            const int row = s >> 2;                                             \
            const int sc = (s & 3) ^ ((s >> 3) & 3);                            \
            int gr = brow + row; gr = gr < M ? gr : M - 1;                      \
            const float* p = Af + (size_t)gr * K + (kt) + sc * 8;               \
            ar[g][0] = *(const float4*)p;                                       \
            ar[g][1] = *(const float4*)(p + 4);                                 \
        }                                                                       \
    }
#define WRITE_A32(buf)                                                          \
    {                                                                           \
        _Pragma("unroll") for (int g = 0; g < 2; ++g) {                         \
            ushort8 u;                                                          \
            u[0] = f2b(ar[g][0].x); u[1] = f2b(ar[g][0].y);                     \
            u[2] = f2b(ar[g][0].z); u[3] = f2b(ar[g][0].w);                     \
            u[4] = f2b(ar[g][1].x); u[5] = f2b(ar[g][1].y);                     \
            u[6] = f2b(ar[g][1].z); u[7] = f2b(ar[g][1].w);                     \
            *(ushort8*)&lds[(buf) * 4096 + (g * 256 + tid) * 8] = u;            \
        }                                                                       \
    }

    const int nt = K / 32;  // 16

    // prologue: tile 0 -> buf 0
    if (A32) {
        LOAD_A32(0);
        STAGE_B(0, 0);
        WRITE_A32(0);
    } else {
        STAGE_A16(0, 0);
        STAGE_B(0, 0);
    }
    __syncthreads();

    int cur = 0;
    for (int t = 0; t < nt; ++t) {
        const bool more = (t + 1 < nt);
        if (more) {
            if (A32) {
                LOAD_A32((t + 1) * 32);   // issue-early; cvt+ds_write after MFMAs
            } else {
                STAGE_A16(cur ^ 1, (t + 1) * 32);
            }
            STAGE_B(cur ^ 1, (t + 1) * 32);
        }

        bf16x8 af[4], bf[4];
#pragma unroll
        for (int mi = 0; mi < 4; ++mi) {
            const int row = wr * 64 + mi * 16 + llo;
            af[mi] = *(const bf16x8*)&lds[cur * 4096 + row * 32 + ((lhi ^ ((row >> 1) & 3)) * 8)];
        }
#pragma unroll
        for (int ni = 0; ni < 4; ++ni) {
            const int row = wc * 64 + ni * 16 + llo;
            bf[ni] = *(const bf16x8*)&lds[8192 + cur * 4096 + row * 32 + ((lhi ^ ((row >> 1) & 3)) * 8)];
        }
#pragma unroll
        for (int mi = 0; mi < 4; ++mi)
#pragma unroll
            for (int ni = 0; ni < 4; ++ni)
                acc[mi][ni] = __builtin_amdgcn_mfma_f32_16x16x32_bf16(
                    af[mi], bf[ni], acc[mi][ni], 0, 0, 0);

        if (A32 && more) WRITE_A32(cur ^ 1);

        __syncthreads();
        cur ^= 1;
    }
#undef STAGE_A16
#undef STAGE_B
#undef LOAD_A32
#undef WRITE_A32

    // epilogue: rowscale, per-wave 64x64 swizzled LDS tile, dwordx4 stores
    short* cws = &lds[wid * 4096];  // [64 rows][8 chunks of 8], chunk ^= (row&7)

#pragma unroll
    for (int mi = 0; mi < 4; ++mi) {
#pragma unroll
        for (int r = 0; r < 4; ++r) {
            const int lrow = mi * 16 + lhi * 4 + r;
            int grow = brow + wr * 64 + lrow;
            grow = grow < M ? grow : M - 1;
            const float ds = rowscale[grow];
#pragma unroll
            for (int ni = 0; ni < 4; ++ni) {
                const int col = ni * 16 + llo;
                const int chunk = (col >> 3) ^ (lrow & 7);
                cws[lrow * 64 + chunk * 8 + (col & 7)] = (short)f2b(acc[mi][ni][r] * ds);
            }
        }
    }
    __syncthreads();

    {
        const int rsub = lane >> 3;
        const int c = lane & 7;
#pragma unroll
        for (int i = 0; i < 8; ++i) {
            const int row = i * 8 + rsub;
            const ushort8 o = *(const ushort8*)&cws[row * 64 + ((c ^ (row & 7)) * 8)];
            const int grow = brow + wr * 64 + row;
            if (grow < M)
                *(ushort8*)(C + (size_t)grow * N + bcol + wc * 64 + c * 8) = o;
        }
    }
}

// ---------------- fused aggregate on pre-scaled H': sum + dinv[d] + bias + ELU ---

template <int D, bool BF16_OUT>
__global__ __launch_bounds__(256) void k_aggregate(const unsigned short* __restrict__ H,
                                                   const float* __restrict__ bias,
                                                   void* __restrict__ outv,
                                                   const int* __restrict__ row_start,
                                                   const int* __restrict__ csr_src,
                                                   const float* __restrict__ dinv) {
    const int wid = threadIdx.x >> 6;
    const int lane = threadIdx.x & 63;
    int n, c0;
    if (D == 512) { n = blockIdx.x * 4 + wid; c0 = lane * 8; }
    else          { n = blockIdx.x * 8 + wid * 2 + (lane >> 5); c0 = (lane & 31) * 8; }
    if (n >= N_NODES) return;

    float acc[8];
    {
        ushort8 v = *(const ushort8*)(H + (size_t)n * D + c0);
#pragma unroll
        for (int e = 0; e < 8; ++e) acc[e] = b2f(v[e]);
    }

    const int e0 = row_start[n];
    const int e1 = row_start[n + 1];
    int j = e0;
    for (; j + 8 <= e1; j += 8) {
        int s[8];
#pragma unroll
        for (int q = 0; q < 8; ++q) s[q] = csr_src[j + q];
#pragma unroll
        for (int h = 0; h < 2; ++h) {
            const ushort8 v0 = *(const ushort8*)(H + (size_t)s[h * 4 + 0] * D + c0);
            const ushort8 v1 = *(const ushort8*)(H + (size_t)s[h * 4 + 1] * D + c0);
            const ushort8 v2 = *(const ushort8*)(H + (size_t)s[h * 4 + 2] * D + c0);
            const ushort8 v3 = *(const ushort8*)(H + (size_t)s[h * 4 + 3] * D + c0);
#pragma unroll
            for (int e = 0; e < 8; ++e) {
                acc[e] += b2f(v0[e]);
                acc[e] += b2f(v1[e]);
                acc[e] += b2f(v2[e]);
                acc[e] += b2f(v3[e]);
            }
        }
    }
    for (; j + 4 <= e1; j += 4) {
        const int s0 = csr_src[j + 0];
        const int s1 = csr_src[j + 1];
        const int s2 = csr_src[j + 2];
        const int s3 = csr_src[j + 3];
        const ushort8 v0 = *(const ushort8*)(H + (size_t)s0 * D + c0);
        const ushort8 v1 = *(const ushort8*)(H + (size_t)s1 * D + c0);
        const ushort8 v2 = *(const ushort8*)(H + (size_t)s2 * D + c0);
        const ushort8 v3 = *(const ushort8*)(H + (size_t)s3 * D + c0);
#pragma unroll
        for (int e = 0; e < 8; ++e) {
            acc[e] += b2f(v0[e]);
            acc[e] += b2f(v1[e]);
            acc[e] += b2f(v2[e]);
            acc[e] += b2f(v3[e]);
        }
    }
    for (; j < e1; ++j) {
        const int s = csr_src[j];
        const ushort8 v = *(const ushort8*)(H + (size_t)s * D + c0);
#pragma unroll
        for (int e = 0; e < 8; ++e) acc[e] += b2f(v[e]);
    }

    const float di = dinv[n];
#pragma unroll
    for (int e = 0; e < 8; ++e) {
        float t = fmaf(acc[e], di, bias[c0 + e]);
        acc[e] = t > 0.f ? t : expf(t) - 1.f;
    }

    if (BF16_OUT) {
        ushort8 o;
#pragma unroll
        for (int e = 0; e < 8; ++e) o[e] = f2b(acc[e]);
        *(ushort8*)((unsigned short*)outv + (size_t)n * D + c0) = o;
    } else {
        float* orow = (float*)outv + (size_t)n * D + c0;
        *(float4*)orow = make_float4(acc[0], acc[1], acc[2], acc[3]);
        *(float4*)(orow + 4) = make_float4(acc[4], acc[5], acc[6], acc[7]);
    }
}

// ---------------- launch ----------------

extern "C" void kernel_launch(void* const* d_in, const int* in_sizes, int n_in,
                              void* d_out, int out_size, void* d_ws, size_t ws_size,
                              hipStream_t stream) {
    const float* x  = (const float*)d_in[0];
    const int* ei   = (const int*)d_in[1];
    const int* src  = ei;
    const int* dst  = ei + N_EDGES;
    const float* W1 = (const float*)d_in[2];
    const float* b1 = (const float*)d_in[3];
    const float* W2 = (const float*)d_in[4];
    const float* b2 = (const float*)d_in[5];
    float* out = (float*)d_out;

    char* ws = (char*)d_ws;
    size_t off = 0;
    auto alloc = [&](size_t bytes) -> void* {
        void* p = ws + off;
        off = (off + bytes + 255) & ~(size_t)255;
        return p;
    };
    int*   indeg     = (int*)alloc((size_t)N_NODES * 4);
    int*   bsum      = (int*)alloc((size_t)NB * 4);
    int*   boff      = (int*)alloc((size_t)NB * 4);
    int*   row_start = (int*)alloc((size_t)(N_NODES + 1) * 4);
    int*   cursor    = (int*)alloc((size_t)N_NODES * 4);
    int*   csr_src   = (int*)alloc((size_t)N_EDGES * 4);
    float* dinv      = (float*)alloc((size_t)N_NODES * 4);
    unsigned short* W1t  = (unsigned short*)alloc((size_t)D_H * D_IN * 2);
    unsigned short* W2t  = (unsigned short*)alloc((size_t)D_OUT * D_H * 2);
    unsigned short* H1   = (unsigned short*)alloc((size_t)N_NODES * D_H * 2);   // 51.2 MB
    unsigned short* out1 = (unsigned short*)alloc((size_t)N_NODES * D_H * 2);   // 51.2 MB
    unsigned short* H2   = (unsigned short*)alloc((size_t)N_NODES * D_OUT * 2); // 25.6 MB

    // L0: zero indeg (must precede atomics) — stream-ordered memset
    hipMemsetAsync(indeg, 0, (size_t)N_NODES * 4, stream);
    // L1: fused indeg-hist + weight transposes
    k_prep<<<NBK + W1B + W2B, 256, 0, stream>>>(W1, W1t, W2, W2t, dst, indeg);
    // L2-4: scan chain -> row_start/cursor/dinv
    k_partials<<<NB, 256, 0, stream>>>(indeg, bsum);
    k_scanb<<<1, 256, 0, stream>>>(bsum, boff);
    k_finalize<<<NB, 256, 0, stream>>>(indeg, boff, row_start, cursor, dinv);

    const int nrb = (N_NODES + 127) / 128;  // 391
    const int rgrp = (nrb + 7) / 8;         // 49

    // ----- layer 1 (A = x fp32 direct; bucket fused into GEMM1 launch) -----
    {
        const int ncb = D_H / 128;          // 4
        k_gemm<true, true><<<NBK + 8 * ncb * rgrp, 256, 0, stream>>>(
            x, W1t, H1, dinv, N_NODES, D_H, D_IN, ncb, nrb, src, dst, cursor, csr_src);
    }
    k_aggregate<512, true><<<(N_NODES + 3) / 4, 256, 0, stream>>>(H1, b1, out1, row_start, csr_src, dinv);

    // ----- layer 2 -----
    {
        const int ncb = D_OUT / 128;        // 2
        k_gemm<false, false><<<8 * ncb * rgrp, 256, 0, stream>>>(
            out1, W2t, H2, dinv, N_NODES, D_OUT, D_H, ncb, nrb, nullptr, nullptr, nullptr, nullptr);
    }
    k_aggregate<256, false><<<(N_NODES + 7) / 8, 256, 0, stream>>>(H2, b2, out, row_start, csr_src, dinv);
}